// Round 2
// baseline (394.848 us; speedup 1.0000x reference)
//
#include <hip/hip_runtime.h>
#include <hip/hip_bf16.h>

// ---------------------------------------------------------------------------
// B=1024, T=31, L=30, H=64, OUT_STEPS=20
// conv1 1->4 3x3 VALID relu pool2 : 32->30->15
// conv2 4->10 3x3 VALID relu pool2: 15->13->6 ; fc 360->5
// enc GRU in=9 H=64 (30 steps); dec GRU in=4 H=64 (20 steps) + lin 64->4
// out[b][t][d] = cumsum over t + bbox[b][30][d]
// ---------------------------------------------------------------------------

#define B_    1024
#define L_    30
#define H_    64

__device__ __forceinline__ float sigmoid_f(float v) {
    return 1.f / (1.f + __expf(-v));
}
__device__ __forceinline__ float tanh_f(float v) {
    v = fminf(fmaxf(v, -15.f), 15.f);
    float e = __expf(2.f * v);
    return (e - 1.f) / (e + 1.f);
}
__device__ __forceinline__ void load4_lds(float* r, const float* p) {
    // p is 8B-aligned by construction
    float2 a = *(const float2*)p;
    float2 b = *(const float2*)(p + 2);
    r[0] = a.x; r[1] = a.y; r[2] = b.x; r[3] = b.y;
}

// ---------------------------------------------------------------------------
// Kernel A: conv encoder. One 64-thread block per image.
// Thread = pooled output pixel, computes ALL output channels:
//   stage1 weights are wave-uniform -> scalar loads; stage2 weights prepacked
//   into LDS, 2 oc per (pixel,ocp) unit. Padded LDS strides break conflicts.
// ---------------------------------------------------------------------------
__global__ __launch_bounds__(64) void conv_embed_kernel(
    const float* __restrict__ bbox,
    const float* __restrict__ head,
    const float* __restrict__ c1w, const float* __restrict__ c1b,
    const float* __restrict__ c2w, const float* __restrict__ c2b,
    const float* __restrict__ fcw, const float* __restrict__ fcb,
    float* __restrict__ enc_in)
{
    const int img = blockIdx.x;          // 0..30719
    const int b = img / L_;
    const int l = img % L_;
    const int tid = threadIdx.x;

    __shared__ float s_img[32 * 36];     // row stride 36 (bank spread, 16B align)
    __shared__ float s_p1[15 * 17 * 4];  // [py][px][ic], px stride 4, py stride 68
    __shared__ float s_w2[10 * 4 * 12];  // [oc][ic][k pad 12]
    __shared__ float s_b2[10];
    __shared__ float s_p2[360];          // [oc][py][px] flat
    __shared__ float s_red[64];

    // ---- load image (row stride 36) + prepack conv2 weights ----------------
    {
        const float4* src = (const float4*)(head + ((size_t)b * 31 + (size_t)l) * 1024);
        #pragma unroll
        for (int i = 0; i < 4; ++i) {
            const int g = 4 * (tid + 64 * i);            // 0..1020 step 4
            float4 v = src[tid + 64 * i];
            *(float4*)&s_img[(g >> 5) * 36 + (g & 31)] = v;   // 16B aligned
        }
        for (int idx = tid; idx < 360; idx += 64) {
            const int oc = idx / 36, r = idx % 36;
            const int ic = r / 9, k = r % 9;
            s_w2[(oc * 4 + ic) * 12 + k] = c2w[idx];
        }
        if (tid < 10) s_b2[tid] = c2b[tid];
    }
    __syncthreads();

    // ---- stage 1: conv1 + relu + pool. thread-iter = pooled pixel ----------
    {
        float w1[36], b1[4];
        #pragma unroll
        for (int k = 0; k < 36; ++k) w1[k] = c1w[k];     // uniform -> scalar
        #pragma unroll
        for (int k = 0; k < 4; ++k) b1[k] = c1b[k];

        #pragma unroll
        for (int it = 0; it < 4; ++it) {
            const int p = tid + 64 * it;
            if (p < 225) {
                const int py = p / 15, px = p % 15;
                const int y0 = 2 * py, x0 = 2 * px;
                float r[4][4];
                #pragma unroll
                for (int rr = 0; rr < 4; ++rr)
                    load4_lds(r[rr], &s_img[(y0 + rr) * 36 + x0]);
                float4 outv;
                #pragma unroll
                for (int oc = 0; oc < 4; ++oc) {
                    float a00 = b1[oc], a01 = b1[oc], a10 = b1[oc], a11 = b1[oc];
                    #pragma unroll
                    for (int ky = 0; ky < 3; ++ky) {
                        #pragma unroll
                        for (int kx = 0; kx < 3; ++kx) {
                            const float w = w1[oc * 9 + ky * 3 + kx];
                            a00 = fmaf(w, r[ky][kx],         a00);
                            a01 = fmaf(w, r[ky][kx + 1],     a01);
                            a10 = fmaf(w, r[ky + 1][kx],     a10);
                            a11 = fmaf(w, r[ky + 1][kx + 1], a11);
                        }
                    }
                    a00 = fmaxf(a00, 0.f); a01 = fmaxf(a01, 0.f);
                    a10 = fmaxf(a10, 0.f); a11 = fmaxf(a11, 0.f);
                    ((float*)&outv)[oc] = fmaxf(fmaxf(a00, a01), fmaxf(a10, a11));
                }
                *(float4*)&s_p1[(py * 17 + px) * 4] = outv;
            }
        }
    }
    __syncthreads();

    // ---- stage 2: conv2 + relu + pool. unit = (pooled pixel, oc pair) ------
    #pragma unroll
    for (int it = 0; it < 3; ++it) {
        const int u = tid + 64 * it;
        if (u < 180) {
            const int pix = u / 5, ocp = u % 5;          // lanes 0-4 share pix
            const int ppy = pix / 6, ppx = pix % 6;
            const int y0 = 2 * ppy, x0 = 2 * ppx;
            float4 P[4][4];                               // [row][col] = 4 ic
            #pragma unroll
            for (int rr = 0; rr < 4; ++rr)
                #pragma unroll
                for (int cc = 0; cc < 4; ++cc)
                    P[rr][cc] = *(const float4*)&s_p1[((y0 + rr) * 17 + (x0 + cc)) * 4];

            const int oc0 = 2 * ocp;
            float a[2][4];
            #pragma unroll
            for (int o = 0; o < 2; ++o) {
                const float bias = s_b2[oc0 + o];
                #pragma unroll
                for (int q = 0; q < 4; ++q) a[o][q] = bias;
            }
            #pragma unroll
            for (int ic = 0; ic < 4; ++ic) {
                float wk[2][12];
                #pragma unroll
                for (int o = 0; o < 2; ++o) {
                    const float* wb = &s_w2[((oc0 + o) * 4 + ic) * 12];
                    *(float4*)&wk[o][0] = *(const float4*)&wb[0];
                    *(float4*)&wk[o][4] = *(const float4*)&wb[4];
                    *(float4*)&wk[o][8] = *(const float4*)&wb[8];
                }
                #pragma unroll
                for (int ky = 0; ky < 3; ++ky) {
                    #pragma unroll
                    for (int kx = 0; kx < 3; ++kx) {
                        const float p00 = ((const float*)&P[ky][kx])[ic];
                        const float p01 = ((const float*)&P[ky][kx + 1])[ic];
                        const float p10 = ((const float*)&P[ky + 1][kx])[ic];
                        const float p11 = ((const float*)&P[ky + 1][kx + 1])[ic];
                        #pragma unroll
                        for (int o = 0; o < 2; ++o) {
                            const float w = wk[o][ky * 3 + kx];
                            a[o][0] = fmaf(w, p00, a[o][0]);
                            a[o][1] = fmaf(w, p01, a[o][1]);
                            a[o][2] = fmaf(w, p10, a[o][2]);
                            a[o][3] = fmaf(w, p11, a[o][3]);
                        }
                    }
                }
            }
            #pragma unroll
            for (int o = 0; o < 2; ++o) {
                float m0 = fmaxf(fmaxf(a[o][0], 0.f), fmaxf(a[o][1], 0.f));
                float m1 = fmaxf(fmaxf(a[o][2], 0.f), fmaxf(a[o][3], 0.f));
                s_p2[(oc0 + o) * 36 + ppy * 6 + ppx] = fmaxf(m0, m1);
            }
        }
    }
    __syncthreads();

    // ---- stage 3: fc 360->5 ------------------------------------------------
    if (tid < 60) {
        const int o = tid / 12, i0 = tid % 12;
        const float* wrow = fcw + o * 360;
        float acc = 0.f;
        #pragma unroll
        for (int k = 0; k < 30; ++k) {
            const int i = i0 + 12 * k;
            acc = fmaf(wrow[i], s_p2[i], acc);
        }
        s_red[tid] = acc;
    }
    __syncthreads();

    float* dst = enc_in + ((size_t)b * L_ + l) * 9;
    if (tid < 5) {
        float acc = fcb[tid];
        #pragma unroll
        for (int k = 0; k < 12; ++k) acc += s_red[tid * 12 + k];
        dst[4 + tid] = acc;
    } else if (tid >= 8 && tid < 12) {
        const int d = tid - 8;
        const float* bb = bbox + (size_t)b * 124 + (size_t)l * 4;
        dst[d] = bb[4 + d] - bb[d];
    }
}

// ---------------------------------------------------------------------------
// Kernel B: GRU encoder. ONE WAVE per batch element, barrier-free.
// Thread j holds h_j and whh rows (192 VGPRs); matvec via __shfl broadcast.
// 128-thread blocks = 2 independent waves.
// ---------------------------------------------------------------------------
__global__ __launch_bounds__(128) void gru_enc_kernel(
    const float* __restrict__ enc_in,   // [1024][30][9]
    const float* __restrict__ wih,      // [192][9]
    const float* __restrict__ whh,      // [192][64]
    const float* __restrict__ bih,
    const float* __restrict__ bhh,
    float* __restrict__ hn)             // [1024][64]
{
    const int w = threadIdx.x >> 6, j = threadIdx.x & 63;
    const int b = blockIdx.x * 2 + w;

    float Wh[3][64];
    #pragma unroll
    for (int g = 0; g < 3; ++g) {
        const float4* row = (const float4*)(whh + (size_t)(g * 64 + j) * 64);
        #pragma unroll
        for (int k4 = 0; k4 < 16; ++k4) *(float4*)&Wh[g][4 * k4] = row[k4];
    }
    float Wi[3][9];
    #pragma unroll
    for (int g = 0; g < 3; ++g) {
        const float* row = wih + (g * 64 + j) * 9;
        #pragma unroll
        for (int k = 0; k < 9; ++k) Wi[g][k] = row[k];
    }
    const float bi0 = bih[j], bi1 = bih[64 + j], bi2 = bih[128 + j];
    const float bh0 = bhh[j], bh1 = bhh[64 + j], bh2 = bhh[128 + j];

    float h = 0.f;
    const float* xp = enc_in + (size_t)b * (L_ * 9);

    for (int t = 0; t < L_; ++t) {
        float gr = bi0 + bh0, gz = bi1 + bh1, gni = bi2, gnh = bh2;
        #pragma unroll
        for (int k = 0; k < 9; ++k) {
            const float xk = xp[t * 9 + k];
            gr  = fmaf(Wi[0][k], xk, gr);
            gz  = fmaf(Wi[1][k], xk, gz);
            gni = fmaf(Wi[2][k], xk, gni);
        }
        #pragma unroll
        for (int k = 0; k < 64; ++k) {
            const float hk = __shfl(h, k);
            gr  = fmaf(Wh[0][k], hk, gr);
            gz  = fmaf(Wh[1][k], hk, gz);
            gnh = fmaf(Wh[2][k], hk, gnh);
        }
        const float r = sigmoid_f(gr);
        const float z = sigmoid_f(gz);
        const float n = tanh_f(gni + r * gnh);
        h = (1.f - z) * n + z * h;
    }
    hn[(size_t)b * H_ + j] = h;
}

// ---------------------------------------------------------------------------
// Kernel C: autoregressive decoder + lin head + cumsum + offset.
// Same one-wave-per-element structure; lin-head reduce via __shfl_xor.
// ---------------------------------------------------------------------------
__global__ __launch_bounds__(128) void gru_dec_kernel(
    const float* __restrict__ bbox,     // [1024][31][4]
    const float* __restrict__ hn,       // [1024][64]
    const float* __restrict__ wih,      // [192][4]
    const float* __restrict__ whh,      // [192][64]
    const float* __restrict__ bih,
    const float* __restrict__ bhh,
    const float* __restrict__ linw,     // [4][64]
    const float* __restrict__ linb,
    float* __restrict__ out)            // [1024][20][4]
{
    const int w = threadIdx.x >> 6, j = threadIdx.x & 63;
    const int b = blockIdx.x * 2 + w;

    float Wh[3][64];
    #pragma unroll
    for (int g = 0; g < 3; ++g) {
        const float4* row = (const float4*)(whh + (size_t)(g * 64 + j) * 64);
        #pragma unroll
        for (int k4 = 0; k4 < 16; ++k4) *(float4*)&Wh[g][4 * k4] = row[k4];
    }
    float Wi[3][4];
    #pragma unroll
    for (int g = 0; g < 3; ++g) {
        const float* row = wih + (g * 64 + j) * 4;
        #pragma unroll
        for (int k = 0; k < 4; ++k) Wi[g][k] = row[k];
    }
    const float bi0 = bih[j], bi1 = bih[64 + j], bi2 = bih[128 + j];
    const float bh0 = bhh[j], bh1 = bhh[64 + j], bh2 = bhh[128 + j];
    const float lw0 = linw[j], lw1 = linw[64 + j], lw2 = linw[128 + j], lw3 = linw[192 + j];
    const float lb0 = linb[0], lb1 = linb[1], lb2 = linb[2], lb3 = linb[3];

    float h = hn[(size_t)b * H_ + j];
    const float* bb = bbox + (size_t)b * 124;
    float px0 = bb[120] - bb[116];
    float px1 = bb[121] - bb[117];
    float px2 = bb[122] - bb[118];
    float px3 = bb[123] - bb[119];
    const float of0 = bb[120], of1 = bb[121], of2 = bb[122], of3 = bb[123];
    float cs0 = 0.f, cs1 = 0.f, cs2 = 0.f, cs3 = 0.f;

    float4* outp = (float4*)(out + (size_t)b * 80);

    for (int t = 0; t < 20; ++t) {
        float gr = bi0 + bh0, gz = bi1 + bh1, gni = bi2, gnh = bh2;
        gr  = fmaf(Wi[0][0], px0, fmaf(Wi[0][1], px1, fmaf(Wi[0][2], px2, fmaf(Wi[0][3], px3, gr))));
        gz  = fmaf(Wi[1][0], px0, fmaf(Wi[1][1], px1, fmaf(Wi[1][2], px2, fmaf(Wi[1][3], px3, gz))));
        gni = fmaf(Wi[2][0], px0, fmaf(Wi[2][1], px1, fmaf(Wi[2][2], px2, fmaf(Wi[2][3], px3, gni))));
        #pragma unroll
        for (int k = 0; k < 64; ++k) {
            const float hk = __shfl(h, k);
            gr  = fmaf(Wh[0][k], hk, gr);
            gz  = fmaf(Wh[1][k], hk, gz);
            gnh = fmaf(Wh[2][k], hk, gnh);
        }
        const float r = sigmoid_f(gr);
        const float z = sigmoid_f(gz);
        const float n = tanh_f(gni + r * gnh);
        h = (1.f - z) * n + z * h;

        float v0 = lw0 * h, v1 = lw1 * h, v2 = lw2 * h, v3 = lw3 * h;
        #pragma unroll
        for (int s = 32; s > 0; s >>= 1) {
            v0 += __shfl_xor(v0, s);
            v1 += __shfl_xor(v1, s);
            v2 += __shfl_xor(v2, s);
            v3 += __shfl_xor(v3, s);
        }
        px0 = v0 + lb0 + px0;
        px1 = v1 + lb1 + px1;
        px2 = v2 + lb2 + px2;
        px3 = v3 + lb3 + px3;
        cs0 += px0; cs1 += px1; cs2 += px2; cs3 += px3;
        if (j == 0) outp[t] = make_float4(cs0 + of0, cs1 + of1, cs2 + of2, cs3 + of3);
    }
}

// ---------------------------------------------------------------------------
extern "C" void kernel_launch(void* const* d_in, const int* in_sizes, int n_in,
                              void* d_out, int out_size, void* d_ws, size_t ws_size,
                              hipStream_t stream) {
    (void)in_sizes; (void)n_in; (void)out_size; (void)ws_size;
    const float* bbox = (const float*)d_in[0];
    const float* head = (const float*)d_in[1];
    const float* c1w  = (const float*)d_in[2];
    const float* c1b  = (const float*)d_in[3];
    const float* c2w  = (const float*)d_in[4];
    const float* c2b  = (const float*)d_in[5];
    const float* fcw  = (const float*)d_in[6];
    const float* fcb  = (const float*)d_in[7];
    const float* ewih = (const float*)d_in[8];
    const float* ewhh = (const float*)d_in[9];
    const float* ebih = (const float*)d_in[10];
    const float* ebhh = (const float*)d_in[11];
    const float* dwih = (const float*)d_in[12];
    const float* dwhh = (const float*)d_in[13];
    const float* dbih = (const float*)d_in[14];
    const float* dbhh = (const float*)d_in[15];
    const float* linw = (const float*)d_in[16];
    const float* linb = (const float*)d_in[17];
    float* out = (float*)d_out;

    float* enc_in = (float*)d_ws;                       // 1024*30*9 floats
    float* hn     = enc_in + (size_t)B_ * L_ * 9;       // 1024*64 floats

    conv_embed_kernel<<<B_ * L_, 64, 0, stream>>>(bbox, head, c1w, c1b, c2w, c2b,
                                                  fcw, fcb, enc_in);
    gru_enc_kernel<<<B_ / 2, 128, 0, stream>>>(enc_in, ewih, ewhh, ebih, ebhh, hn);
    gru_dec_kernel<<<B_ / 2, 128, 0, stream>>>(bbox, hn, dwih, dwhh, dbih, dbhh,
                                               linw, linb, out);
}

// Round 3
// 322.398 us; speedup vs baseline: 1.2247x; 1.2247x over previous
//
#include <hip/hip_runtime.h>
#include <hip/hip_bf16.h>

// ---------------------------------------------------------------------------
// B=1024, T=31, L=30, H=64, OUT_STEPS=20
// conv1 1->4 3x3 VALID relu pool2 : 32->30->15
// conv2 4->10 3x3 VALID relu pool2: 15->13->6 ; fc 360->5
// enc GRU in=9 H=64 (30 steps); dec GRU in=4 H=64 (20 steps) + lin 64->4
// out[b][t][d] = cumsum over t + bbox[b][30][d]
// ---------------------------------------------------------------------------

#define B_    1024
#define L_    30
#define H_    64

__device__ __forceinline__ float sigmoid_f(float v) {
    return 1.f / (1.f + __expf(-v));
}
__device__ __forceinline__ float tanh_f(float v) {
    v = fminf(fmaxf(v, -15.f), 15.f);
    float e = __expf(2.f * v);
    return (e - 1.f) / (e + 1.f);
}
__device__ __forceinline__ float bcast(float v, int lane) {
    // lane is a compile-time literal at every call site -> v_readlane (SGPR bcast)
    return __int_as_float(__builtin_amdgcn_readlane(__float_as_int(v), lane));
}
__device__ __forceinline__ void load4_lds(float* r, const float* p) {
    float2 a = *(const float2*)p;
    float2 b = *(const float2*)(p + 2);
    r[0] = a.x; r[1] = a.y; r[2] = b.x; r[3] = b.y;
}

// ---------------------------------------------------------------------------
// Kernel A (round-1 version, measured 90 us, VALU-issue-bound):
// per-image conv encoder + fc -> enc_in[b][l][4..8]; diffs -> [0..3]
// ---------------------------------------------------------------------------
__global__ __launch_bounds__(64) void conv_embed_kernel(
    const float* __restrict__ bbox,
    const float* __restrict__ head,
    const float* __restrict__ c1w, const float* __restrict__ c1b,
    const float* __restrict__ c2w, const float* __restrict__ c2b,
    const float* __restrict__ fcw, const float* __restrict__ fcb,
    float* __restrict__ enc_in)
{
    const int img = blockIdx.x;          // 0..30719
    const int b = img / L_;
    const int l = img % L_;
    const int tid = threadIdx.x;

    __shared__ float s_img[32 * 32];
    __shared__ float s_p1[4 * 15 * 16];  // [c][py][px], width padded to 16
    __shared__ float s_p2[360];
    __shared__ float s_red[60];

    {
        const float4* src = (const float4*)(head + ((size_t)b * 31 + (size_t)l) * 1024);
        float4* dst = (float4*)s_img;
        #pragma unroll
        for (int i = 0; i < 4; ++i) dst[tid + 64 * i] = src[tid + 64 * i];
    }
    __syncthreads();

    // stage 1: conv1 + relu + pool; thread = (c, px), rolling 4-row window
    if (tid < 60) {
        const int c = tid / 15, px = tid % 15;
        const int x0 = 2 * px;
        float w[9];
        #pragma unroll
        for (int k = 0; k < 9; ++k) w[k] = c1w[c * 9 + k];
        const float bias = c1b[c];

        float r0[4], r1[4], r2[4], r3[4];
        load4_lds(r0, s_img + 0 * 32 + x0);
        load4_lds(r1, s_img + 1 * 32 + x0);
        #pragma unroll
        for (int py = 0; py < 15; ++py) {
            load4_lds(r2, s_img + (2 * py + 2) * 32 + x0);
            load4_lds(r3, s_img + (2 * py + 3) * 32 + x0);
            float a00 = bias, a01 = bias, a10 = bias, a11 = bias;
            #pragma unroll
            for (int kx = 0; kx < 3; ++kx) {
                const float w0 = w[kx], w1 = w[3 + kx], w2 = w[6 + kx];
                a00 = fmaf(w0, r0[kx],     fmaf(w1, r1[kx],     fmaf(w2, r2[kx],     a00)));
                a01 = fmaf(w0, r0[kx + 1], fmaf(w1, r1[kx + 1], fmaf(w2, r2[kx + 1], a01)));
                a10 = fmaf(w0, r1[kx],     fmaf(w1, r2[kx],     fmaf(w2, r3[kx],     a10)));
                a11 = fmaf(w0, r1[kx + 1], fmaf(w1, r2[kx + 1], fmaf(w2, r3[kx + 1], a11)));
            }
            a00 = fmaxf(a00, 0.f); a01 = fmaxf(a01, 0.f);
            a10 = fmaxf(a10, 0.f); a11 = fmaxf(a11, 0.f);
            s_p1[c * 240 + py * 16 + px] = fmaxf(fmaxf(a00, a01), fmaxf(a10, a11));
            #pragma unroll
            for (int q = 0; q < 4; ++q) { r0[q] = r2[q]; r1[q] = r3[q]; }
        }
    }
    __syncthreads();

    // stage 2: conv2 + relu + pool; thread = (c, px), rolling window
    if (tid < 60) {
        const int c = tid / 6, px = tid % 6;
        const int x0 = 2 * px;
        float w[4][9];
        #pragma unroll
        for (int ic = 0; ic < 4; ++ic)
            #pragma unroll
            for (int k = 0; k < 9; ++k) w[ic][k] = c2w[(c * 4 + ic) * 9 + k];
        const float bias = c2b[c];

        float win[4][4][4];
        #pragma unroll
        for (int ic = 0; ic < 4; ++ic) {
            load4_lds(win[0][ic], s_p1 + ic * 240 + 0 * 16 + x0);
            load4_lds(win[1][ic], s_p1 + ic * 240 + 1 * 16 + x0);
        }
        #pragma unroll
        for (int py = 0; py < 6; ++py) {
            #pragma unroll
            for (int ic = 0; ic < 4; ++ic) {
                load4_lds(win[2][ic], s_p1 + ic * 240 + (2 * py + 2) * 16 + x0);
                load4_lds(win[3][ic], s_p1 + ic * 240 + (2 * py + 3) * 16 + x0);
            }
            float a00 = bias, a01 = bias, a10 = bias, a11 = bias;
            #pragma unroll
            for (int ic = 0; ic < 4; ++ic) {
                #pragma unroll
                for (int kx = 0; kx < 3; ++kx) {
                    const float w0 = w[ic][kx], w1 = w[ic][3 + kx], w2 = w[ic][6 + kx];
                    a00 = fmaf(w0, win[0][ic][kx],     fmaf(w1, win[1][ic][kx],     fmaf(w2, win[2][ic][kx],     a00)));
                    a01 = fmaf(w0, win[0][ic][kx + 1], fmaf(w1, win[1][ic][kx + 1], fmaf(w2, win[2][ic][kx + 1], a01)));
                    a10 = fmaf(w0, win[1][ic][kx],     fmaf(w1, win[2][ic][kx],     fmaf(w2, win[3][ic][kx],     a10)));
                    a11 = fmaf(w0, win[1][ic][kx + 1], fmaf(w1, win[2][ic][kx + 1], fmaf(w2, win[3][ic][kx + 1], a11)));
                }
            }
            a00 = fmaxf(a00, 0.f); a01 = fmaxf(a01, 0.f);
            a10 = fmaxf(a10, 0.f); a11 = fmaxf(a11, 0.f);
            s_p2[c * 36 + py * 6 + px] = fmaxf(fmaxf(a00, a01), fmaxf(a10, a11));
            #pragma unroll
            for (int ic = 0; ic < 4; ++ic)
                #pragma unroll
                for (int q = 0; q < 4; ++q) { win[0][ic][q] = win[2][ic][q]; win[1][ic][q] = win[3][ic][q]; }
        }
    }
    __syncthreads();

    // stage 3: fc 360->5
    if (tid < 60) {
        const int o = tid / 12, i0 = tid % 12;
        const float* wrow = fcw + o * 360;
        float acc = 0.f;
        #pragma unroll
        for (int k = 0; k < 30; ++k) {
            const int i = i0 + 12 * k;
            acc = fmaf(wrow[i], s_p2[i], acc);
        }
        s_red[tid] = acc;
    }
    __syncthreads();

    float* dst = enc_in + ((size_t)b * L_ + l) * 9;
    if (tid < 5) {
        float acc = fcb[tid];
        #pragma unroll
        for (int k = 0; k < 12; ++k) acc += s_red[tid * 12 + k];
        dst[4 + tid] = acc;
    } else if (tid >= 8 && tid < 12) {
        const int d = tid - 8;
        const float* bb = bbox + (size_t)b * 124 + (size_t)l * 4;
        dst[d] = bb[4 + d] - bb[d];
    }
}

// ---------------------------------------------------------------------------
// Kernel B: GRU encoder. TWO waves per batch element (128-thr block = 1 elem).
// Wave w2 holds Wh[3][32] (k-half) -> ~96 weight VGPRs, no spill.
// h replicated per wave; broadcast via v_readlane (literal lanes).
// One barrier/step, double-buffered LDS partials.
// ---------------------------------------------------------------------------
__global__ __launch_bounds__(128) void gru_enc_kernel(
    const float* __restrict__ enc_in,   // [1024][30][9]
    const float* __restrict__ wih,      // [192][9]
    const float* __restrict__ whh,      // [192][64]
    const float* __restrict__ bih,
    const float* __restrict__ bhh,
    float* __restrict__ hn)             // [1024][64]
{
    const int j  = threadIdx.x & 63;
    const int w2 = threadIdx.x >> 6;    // k-half
    const int b  = blockIdx.x;

    float Wh[3][32];
    #pragma unroll
    for (int g = 0; g < 3; ++g) {
        const float4* row = (const float4*)(whh + (size_t)(g * 64 + j) * 64 + 32 * w2);
        #pragma unroll
        for (int k4 = 0; k4 < 8; ++k4) *(float4*)&Wh[g][4 * k4] = row[k4];
    }
    float Wi[3][9];
    #pragma unroll
    for (int g = 0; g < 3; ++g) {
        const float* row = wih + (g * 64 + j) * 9;
        #pragma unroll
        for (int k = 0; k < 9; ++k) Wi[g][k] = row[k];
    }
    const float bi0 = bih[j], bi1 = bih[64 + j], bi2 = bih[128 + j];
    const float bh0 = bhh[j], bh1 = bhh[64 + j], bh2 = bhh[128 + j];

    __shared__ float sp[2][2][3][64];   // [buf][wave][gate][j]
    float h = 0.f;
    const float* xp = enc_in + (size_t)b * (L_ * 9);

    float xr[9];
    #pragma unroll
    for (int k = 0; k < 9; ++k) xr[k] = xp[k];

    for (int t = 0; t < L_; ++t) {
        const int pb = t & 1;

        // hidden-side partials over this wave's k-half (literal readlane bcast)
        float pr = 0.f, pz = 0.f, pn = 0.f;
        if (w2 == 0) {
            #pragma unroll
            for (int k = 0; k < 32; ++k) {
                const float hk = bcast(h, k);
                pr = fmaf(Wh[0][k], hk, pr);
                pz = fmaf(Wh[1][k], hk, pz);
                pn = fmaf(Wh[2][k], hk, pn);
            }
        } else {
            #pragma unroll
            for (int k = 0; k < 32; ++k) {
                const float hk = bcast(h, k + 32);
                pr = fmaf(Wh[0][k], hk, pr);
                pz = fmaf(Wh[1][k], hk, pz);
                pn = fmaf(Wh[2][k], hk, pn);
            }
        }
        sp[pb][w2][0][j] = pr;
        sp[pb][w2][1][j] = pz;
        sp[pb][w2][2][j] = pn;

        // input-side gates from prefetched x; prefetch next x
        float gr = bi0 + bh0, gz = bi1 + bh1, gni = bi2;
        #pragma unroll
        for (int k = 0; k < 9; ++k) {
            gr  = fmaf(Wi[0][k], xr[k], gr);
            gz  = fmaf(Wi[1][k], xr[k], gz);
            gni = fmaf(Wi[2][k], xr[k], gni);
        }
        if (t + 1 < L_) {
            #pragma unroll
            for (int k = 0; k < 9; ++k) xr[k] = xp[(t + 1) * 9 + k];
        }

        __syncthreads();
        const float opr = sp[pb][w2 ^ 1][0][j];
        const float opz = sp[pb][w2 ^ 1][1][j];
        const float opn = sp[pb][w2 ^ 1][2][j];

        const float r = sigmoid_f(gr + pr + opr);
        const float z = sigmoid_f(gz + pz + opz);
        const float n = tanh_f(gni + r * (bh2 + pn + opn));
        h = (1.f - z) * n + z * h;
    }
    if (w2 == 0) hn[(size_t)b * H_ + j] = h;
}

// ---------------------------------------------------------------------------
// Kernel C: autoregressive decoder + lin head + cumsum + offset.
// Same 2-wave structure.
// ---------------------------------------------------------------------------
__global__ __launch_bounds__(128) void gru_dec_kernel(
    const float* __restrict__ bbox,     // [1024][31][4]
    const float* __restrict__ hn,       // [1024][64]
    const float* __restrict__ wih,      // [192][4]
    const float* __restrict__ whh,      // [192][64]
    const float* __restrict__ bih,
    const float* __restrict__ bhh,
    const float* __restrict__ linw,     // [4][64]
    const float* __restrict__ linb,
    float* __restrict__ out)            // [1024][20][4]
{
    const int j  = threadIdx.x & 63;
    const int w2 = threadIdx.x >> 6;
    const int b  = blockIdx.x;

    float Wh[3][32];
    #pragma unroll
    for (int g = 0; g < 3; ++g) {
        const float4* row = (const float4*)(whh + (size_t)(g * 64 + j) * 64 + 32 * w2);
        #pragma unroll
        for (int k4 = 0; k4 < 8; ++k4) *(float4*)&Wh[g][4 * k4] = row[k4];
    }
    float Wi[3][4];
    #pragma unroll
    for (int g = 0; g < 3; ++g) {
        const float* row = wih + (g * 64 + j) * 4;
        #pragma unroll
        for (int k = 0; k < 4; ++k) Wi[g][k] = row[k];
    }
    const float bi0 = bih[j], bi1 = bih[64 + j], bi2 = bih[128 + j];
    const float bh0 = bhh[j], bh1 = bhh[64 + j], bh2 = bhh[128 + j];
    const float lw0 = linw[j], lw1 = linw[64 + j], lw2 = linw[128 + j], lw3 = linw[192 + j];
    const float lb0 = linb[0], lb1 = linb[1], lb2 = linb[2], lb3 = linb[3];

    float h = hn[(size_t)b * H_ + j];
    const float* bb = bbox + (size_t)b * 124;
    float px0 = bb[120] - bb[116];
    float px1 = bb[121] - bb[117];
    float px2 = bb[122] - bb[118];
    float px3 = bb[123] - bb[119];
    const float of0 = bb[120], of1 = bb[121], of2 = bb[122], of3 = bb[123];
    float cs0 = 0.f, cs1 = 0.f, cs2 = 0.f, cs3 = 0.f;

    __shared__ float sp[2][2][3][64];
    float4* outp = (float4*)(out + (size_t)b * 80);

    for (int t = 0; t < 20; ++t) {
        const int pb = t & 1;

        float pr = 0.f, pz = 0.f, pn = 0.f;
        if (w2 == 0) {
            #pragma unroll
            for (int k = 0; k < 32; ++k) {
                const float hk = bcast(h, k);
                pr = fmaf(Wh[0][k], hk, pr);
                pz = fmaf(Wh[1][k], hk, pz);
                pn = fmaf(Wh[2][k], hk, pn);
            }
        } else {
            #pragma unroll
            for (int k = 0; k < 32; ++k) {
                const float hk = bcast(h, k + 32);
                pr = fmaf(Wh[0][k], hk, pr);
                pz = fmaf(Wh[1][k], hk, pz);
                pn = fmaf(Wh[2][k], hk, pn);
            }
        }
        sp[pb][w2][0][j] = pr;
        sp[pb][w2][1][j] = pz;
        sp[pb][w2][2][j] = pn;

        float gr = bi0 + bh0, gz = bi1 + bh1, gni = bi2;
        gr  = fmaf(Wi[0][0], px0, fmaf(Wi[0][1], px1, fmaf(Wi[0][2], px2, fmaf(Wi[0][3], px3, gr))));
        gz  = fmaf(Wi[1][0], px0, fmaf(Wi[1][1], px1, fmaf(Wi[1][2], px2, fmaf(Wi[1][3], px3, gz))));
        gni = fmaf(Wi[2][0], px0, fmaf(Wi[2][1], px1, fmaf(Wi[2][2], px2, fmaf(Wi[2][3], px3, gni))));

        __syncthreads();
        const float opr = sp[pb][w2 ^ 1][0][j];
        const float opz = sp[pb][w2 ^ 1][1][j];
        const float opn = sp[pb][w2 ^ 1][2][j];

        const float r = sigmoid_f(gr + pr + opr);
        const float z = sigmoid_f(gz + pz + opz);
        const float n = tanh_f(gni + r * (bh2 + pn + opn));
        h = (1.f - z) * n + z * h;

        // x_new = lin(h) + prev_x ; butterfly over this wave's replicated h
        float v0 = lw0 * h, v1 = lw1 * h, v2 = lw2 * h, v3 = lw3 * h;
        #pragma unroll
        for (int s = 32; s > 0; s >>= 1) {
            v0 += __shfl_xor(v0, s);
            v1 += __shfl_xor(v1, s);
            v2 += __shfl_xor(v2, s);
            v3 += __shfl_xor(v3, s);
        }
        px0 = v0 + lb0 + px0;
        px1 = v1 + lb1 + px1;
        px2 = v2 + lb2 + px2;
        px3 = v3 + lb3 + px3;
        cs0 += px0; cs1 += px1; cs2 += px2; cs3 += px3;
        if (threadIdx.x == 0) outp[t] = make_float4(cs0 + of0, cs1 + of1, cs2 + of2, cs3 + of3);
    }
}

// ---------------------------------------------------------------------------
extern "C" void kernel_launch(void* const* d_in, const int* in_sizes, int n_in,
                              void* d_out, int out_size, void* d_ws, size_t ws_size,
                              hipStream_t stream) {
    (void)in_sizes; (void)n_in; (void)out_size; (void)ws_size;
    const float* bbox = (const float*)d_in[0];
    const float* head = (const float*)d_in[1];
    const float* c1w  = (const float*)d_in[2];
    const float* c1b  = (const float*)d_in[3];
    const float* c2w  = (const float*)d_in[4];
    const float* c2b  = (const float*)d_in[5];
    const float* fcw  = (const float*)d_in[6];
    const float* fcb  = (const float*)d_in[7];
    const float* ewih = (const float*)d_in[8];
    const float* ewhh = (const float*)d_in[9];
    const float* ebih = (const float*)d_in[10];
    const float* ebhh = (const float*)d_in[11];
    const float* dwih = (const float*)d_in[12];
    const float* dwhh = (const float*)d_in[13];
    const float* dbih = (const float*)d_in[14];
    const float* dbhh = (const float*)d_in[15];
    const float* linw = (const float*)d_in[16];
    const float* linb = (const float*)d_in[17];
    float* out = (float*)d_out;

    float* enc_in = (float*)d_ws;                       // 1024*30*9 floats
    float* hn     = enc_in + (size_t)B_ * L_ * 9;       // 1024*64 floats

    conv_embed_kernel<<<B_ * L_, 64, 0, stream>>>(bbox, head, c1w, c1b, c2w, c2b,
                                                  fcw, fcb, enc_in);
    gru_enc_kernel<<<B_, 128, 0, stream>>>(enc_in, ewih, ewhh, ebih, ebhh, hn);
    gru_dec_kernel<<<B_, 128, 0, stream>>>(bbox, hn, dwih, dwhh, dbih, dbhh,
                                           linw, linb, out);
}